// Round 5
// baseline (298.853 us; speedup 1.0000x reference)
//
#include <hip/hip_runtime.h>
#include <hip/hip_bf16.h>

typedef unsigned int  uint;
typedef unsigned short ushort;
typedef short bf16x8 __attribute__((ext_vector_type(8)));
typedef float f32x4  __attribute__((ext_vector_type(4)));

#define HW 4096
#define KD 2304

__device__ __forceinline__ void load_lds16(const void* g, void* l) {
    __builtin_amdgcn_global_load_lds((const __attribute__((address_space(1))) void*)g,
                                     (__attribute__((address_space(3))) void*)l, 16, 0, 0);
}
__device__ __forceinline__ float blo(uint u) { return __uint_as_float(u << 16); }
__device__ __forceinline__ float bhi(uint u) { return __uint_as_float(u & 0xffff0000u); }
__device__ __forceinline__ uint pack2(float e, float o) {
    __hip_bfloat16 he = __float2bfloat16(e), ho = __float2bfloat16(o);
    return (uint)(*(ushort*)&he) | ((uint)(*(ushort*)&ho) << 16);
}

// ---- merged prep: x->x2 (bf16 pairs), w_def->bt, w_off->bt0 ----
__global__ void prep_all(const float* __restrict__ x, const float* __restrict__ w_def,
                         const float* __restrict__ w_off,
                         uint* __restrict__ x2, ushort* __restrict__ bt,
                         ushort* __restrict__ bt0) {
    int gid = blockIdx.x, t = threadIdx.x;
    if (gid < 8192) {
        int idx = gid * 256 + t;
        int a  = idx & 4095;
        int cp = (idx >> 12) & 127;
        int b  = idx >> 19;
        const float* p = x + ((size_t)(b * 256 + 2 * cp)) * HW + a;
        x2[idx] = pack2(p[0], p[HW]);
    } else if (gid < 10496) {
        int idx = (gid - 8192) * 256 + t;
        int c   = idx & 255;
        int tap = (idx >> 8) % 9;
        int o   = idx / KD;
        __hip_bfloat16 h = __float2bfloat16(w_def[(o * 256 + c) * 9 + tap]);
        bt[idx] = *(ushort*)&h;
    } else {
        int idx = (gid - 10496) * 256 + t;
        int c   = idx & 255;
        int tap = (idx >> 8) % 9;
        int j   = idx / KD;
        float v = (j < 18) ? w_off[(j * 256 + c) * 9 + tap] : 0.f;
        __hip_bfloat16 h = __float2bfloat16(v);
        bt0[idx] = *(ushort*)&h;
    }
}

// ---- one kernel: offset conv -> gather+GEMM (producer/consumer) -> grid sync -> BN ----
__global__ __launch_bounds__(512, 4) void fused_all(
        const uint* __restrict__ x2, const ushort* __restrict__ bt,
        const ushort* __restrict__ bt0, const float* __restrict__ b_off,
        const float* __restrict__ gamma, const float* __restrict__ beta,
        float* __restrict__ out, float* __restrict__ stats, uint* __restrict__ counter) {
    int id = blockIdx.x;                       // 256 blocks
    int xcd = id & 7;
    int b = xcd >> 1, h = (xcd & 1) * 32 + (id >> 3);
    int t = threadIdx.x;
    int wv = t >> 6, lane = t & 63;
    int mrow = lane & 15, quad = lane >> 4;

    __shared__ __align__(16) char smem[81920];
    uint*   lX   = (uint*)smem;                // phase1: 24 KB
    ushort* lB0  = (ushort*)(smem + 24576);    // phase1: 36 KB
    float*  sOff = (float*)smem;               // 4.5 KB (after phase1)
    ushort* lAb  = (ushort*)smem;              // phase2: 2 x 8 KB
    ushort* lBb  = (ushort*)(smem + 16384);    // phase2: 2 x 32 KB

    // ================= phase 1: offset conv (all waves stage, waves 0-3 MFMA) ====
    f32x4 acc0[2];
    acc0[0] = {0.f, 0.f, 0.f, 0.f};
    acc0[1] = {0.f, 0.f, 0.f, 0.f};
    for (int cb = 0; cb < 4; ++cb) {
#pragma unroll
        for (int s = 0; s < 3; ++s) {
            int q  = s * 8 + wv;               // 0..23
            int dy = q >> 3;
            int y  = h + dy - 1;
            int dl = (q & 7) * 256 + lane * 4;
            int cp = dl >> 6, w4 = dl & 63;
            if ((unsigned)y < 64u) {
                const uint* src = x2 + ((size_t)(b * 128 + cb * 32 + cp)) * HW + y * 64 + w4;
                load_lds16(src, &lX[q * 256]);
            } else {
                uint4 z = {0u, 0u, 0u, 0u};
                *(uint4*)&lX[q * 256 + lane * 4] = z;
            }
        }
#pragma unroll
        for (int s = 0; s < 5; ++s) {
            int q = s * 8 + wv;                // 0..39, skip >=36
            if (q < 36) {
                int e = q * 512 + lane * 8;
                int o  = e / 576;
                int r  = e - o * 576;
                int chp = r >> 3;
                int ch  = chp ^ (o & 7);
                int tap = ch >> 3, k8 = ch & 7;
                const ushort* src = bt0 + (size_t)o * KD + tap * 256 + cb * 64 + k8 * 8;
                load_lds16(src, &lB0[q * 512]);
            }
        }
        __syncthreads();
        if (wv < 4) {
#pragma unroll
            for (int tap = 0; tap < 9; ++tap) {
                int dy = tap / 3, dx = tap % 3;
                int xx = wv * 16 + mrow + dx - 1;
                bool vx = (unsigned)xx < 64u;
#pragma unroll
                for (int kb = 0; kb < 2; ++kb) {
                    int cp0 = kb * 16 + quad * 4;
                    uint ad[4];
#pragma unroll
                    for (int i = 0; i < 4; ++i)
                        ad[i] = vx ? lX[(dy * 32 + cp0 + i) * 64 + xx] : 0u;
                    bf16x8 af = *(bf16x8*)ad;
#pragma unroll
                    for (int n = 0; n < 2; ++n) {
                        int o = n * 16 + mrow;
                        int chs = tap * 8 + ((kb * 4 + quad) ^ (o & 7));
                        bf16x8 bfr = *(const bf16x8*)&lB0[o * 576 + chs * 8];
                        acc0[n] = __builtin_amdgcn_mfma_f32_16x16x32_bf16(af, bfr, acc0[n], 0, 0, 0);
                    }
                }
            }
        }
        __syncthreads();
    }
    // off -> LDS (reuses lX region, guarded by barrier above)
    if (wv < 4) {
#pragma unroll
        for (int n = 0; n < 2; ++n) {
            int j = n * 16 + mrow;
            if (j < 18) {
                float bias = b_off[j];
                f32x4 v = acc0[n];
                v.x += bias; v.y += bias; v.z += bias; v.w += bias;
                *(f32x4*)&sOff[j * 64 + wv * 16 + quad * 4] = v;
            }
        }
    }
    __syncthreads();

    // producers load their pos's 18 offsets into scalars
    int pw = t & 63;
    int cq = (t >> 6) & 3;
    float oy0=0,oy1=0,oy2=0,oy3=0,oy4=0,oy5=0,oy6=0,oy7=0,oy8=0;
    float ox0=0,ox1=0,ox2=0,ox3=0,ox4=0,ox5=0,ox6=0,ox7=0,ox8=0;
    if (wv >= 4) {
        oy0 = sOff[ 0*64+pw]; ox0 = sOff[ 1*64+pw];
        oy1 = sOff[ 2*64+pw]; ox1 = sOff[ 3*64+pw];
        oy2 = sOff[ 4*64+pw]; ox2 = sOff[ 5*64+pw];
        oy3 = sOff[ 6*64+pw]; ox3 = sOff[ 7*64+pw];
        oy4 = sOff[ 8*64+pw]; ox4 = sOff[ 9*64+pw];
        oy5 = sOff[10*64+pw]; ox5 = sOff[11*64+pw];
        oy6 = sOff[12*64+pw]; ox6 = sOff[13*64+pw];
        oy7 = sOff[14*64+pw]; ox7 = sOff[15*64+pw];
        oy8 = sOff[16*64+pw]; ox8 = sOff[17*64+pw];
    }
    __syncthreads();

    // ================= phase 2: gather (waves 4-7) + GEMM (waves 0-3) ============
    int a0=0,a1=0,a2=0,a3=0;
    float f0=0,f1=0,f2=0,f3=0;

    auto coords = [&](int tap) {
        float oy, ox;
        switch (tap) {
            case 0: oy=oy0; ox=ox0; break;  case 1: oy=oy1; ox=ox1; break;
            case 2: oy=oy2; ox=ox2; break;  case 3: oy=oy3; ox=ox3; break;
            case 4: oy=oy4; ox=ox4; break;  case 5: oy=oy5; ox=ox5; break;
            case 6: oy=oy6; ox=ox6; break;  case 7: oy=oy7; ox=ox7; break;
            default: oy=oy8; ox=ox8; break;
        }
        float py = oy + (float)(tap / 3 + h - 1);
        float px = ox + (float)(tap % 3 + pw - 1);
        float y0f = floorf(py), x0f = floorf(px);
        float wy1 = py - y0f, wx1 = px - x0f;
        float wy0 = 1.f - wy1, wx0 = 1.f - wx1;
        bool vy0 = (y0f >= 0.f) && (y0f <= 63.f);
        bool vy1 = (y0f >= -1.f) && (y0f <= 62.f);
        bool vx0 = (x0f >= 0.f) && (x0f <= 63.f);
        bool vx1 = (x0f >= -1.f) && (x0f <= 62.f);
        int iy0 = min(max((int)y0f, 0), 63),  iy1 = min(max((int)y0f + 1, 0), 63);
        int ix0 = min(max((int)x0f, 0), 63),  ix1 = min(max((int)x0f + 1, 0), 63);
        a0 = iy0 * 64 + ix0; a1 = iy0 * 64 + ix1;
        a2 = iy1 * 64 + ix0; a3 = iy1 * 64 + ix1;
        f0 = wy0 * wx0 * (float)(vy0 && vx0);
        f1 = wy0 * wx1 * (float)(vy0 && vx1);
        f2 = wy1 * wx0 * (float)(vy1 && vx0);
        f3 = wy1 * wx1 * (float)(vy1 && vx1);
    };

    auto stage = [&](int s, int buf) {
        int tap = s >> 2, cb = s & 3;
        const uint* xp = x2 + ((size_t)(b * 128 + cb * 32 + cq * 8)) * HW;
        uint r[8];
#pragma unroll
        for (int j = 0; j < 8; ++j) {
            const uint* p = xp + (size_t)j * HW;
            uint u0 = p[a0], u1 = p[a1], u2 = p[a2], u3 = p[a3];
            float e = f0 * blo(u0) + f1 * blo(u1) + f2 * blo(u2) + f3 * blo(u3);
            float o = f0 * bhi(u0) + f1 * bhi(u1) + f2 * bhi(u2) + f3 * bhi(u3);
            r[j] = pack2(e, o);
        }
        ushort* lA = lAb + buf * 4096;
        *(uint4*)&lA[pw * 64 + (((cq * 2)     ^ (pw & 7)) * 8)] = *(uint4*)&r[0];
        *(uint4*)&lA[pw * 64 + (((cq * 2 + 1) ^ (pw & 7)) * 8)] = *(uint4*)&r[4];
        ushort* lB = lBb + buf * 16384;
        int pt = t - 256;
#pragma unroll
        for (int s2 = 0; s2 < 8; ++s2) {
            int e2 = s2 * 256 + pt;
            int o2 = e2 >> 3, pp = e2 & 7;
            int k8 = pp ^ (o2 & 7);
            const ushort* src = bt + (size_t)o2 * KD + tap * 256 + cb * 64 + k8 * 8;
            load_lds16(src, &lB[(e2 & ~63) * 8]);
        }
    };

    f32x4 acc[4][4];
    if (wv < 4) {
#pragma unroll
        for (int m = 0; m < 4; ++m)
#pragma unroll
            for (int n = 0; n < 4; ++n) acc[m][n] = {0.f, 0.f, 0.f, 0.f};
    } else {
        coords(0);
        stage(0, 0);
    }

    int buf = 0;
    for (int s = 0; s < 36; ++s) {
        __syncthreads();
        if (wv >= 4) {
            int sn = s + 1;
            if (sn < 36) {
                if ((sn & 3) == 0) coords(sn >> 2);
                stage(sn, buf ^ 1);
            }
        } else {
            ushort* lA = lAb + buf * 4096;
            ushort* lB = lBb + buf * 16384;
#pragma unroll
            for (int kb = 0; kb < 2; ++kb) {
                bf16x8 af[4];
#pragma unroll
                for (int m = 0; m < 4; ++m) {
                    int r = m * 16 + mrow;
                    af[m] = *(const bf16x8*)&lA[r * 64 + (((kb * 4 + quad) ^ (r & 7)) * 8)];
                }
#pragma unroll
                for (int n = 0; n < 4; ++n) {
                    int r = wv * 64 + n * 16 + mrow;
                    bf16x8 bfr = *(const bf16x8*)&lB[r * 64 + (((kb * 4 + quad) ^ (r & 7)) * 8)];
#pragma unroll
                    for (int m = 0; m < 4; ++m)
                        acc[m][n] = __builtin_amdgcn_mfma_f32_16x16x32_bf16(af[m], bfr, acc[m][n], 0, 0, 0);
                }
            }
        }
        buf ^= 1;
    }

    // ---- stats accumulation (consumers) ----
    if (wv < 4) {
#pragma unroll
        for (int n = 0; n < 4; ++n) {
            int o = wv * 64 + n * 16 + mrow;
            float ss = 0.f, qq = 0.f;
#pragma unroll
            for (int m = 0; m < 4; ++m) {
                f32x4 v = acc[m][n];
                ss += v.x + v.y + v.z + v.w;
                qq += v.x * v.x + v.y * v.y + v.z * v.z + v.w * v.w;
            }
            ss += __shfl_xor(ss, 16); ss += __shfl_xor(ss, 32);
            qq += __shfl_xor(qq, 16); qq += __shfl_xor(qq, 32);
            if (quad == 0) {
                atomicAdd(&stats[o], ss);
                atomicAdd(&stats[512 + o], qq);
            }
        }
    }
    __threadfence();
    __syncthreads();
    if (t == 0) {
        __hip_atomic_fetch_add(counter, 1u, __ATOMIC_ACQ_REL, __HIP_MEMORY_SCOPE_AGENT);
        while (__hip_atomic_load(counter, __ATOMIC_ACQUIRE, __HIP_MEMORY_SCOPE_AGENT) < 256u) {
            __builtin_amdgcn_s_sleep(2);
        }
    }
    __syncthreads();

    // ---- BN apply from registers + store ----
    if (wv < 4) {
#pragma unroll
        for (int n = 0; n < 4; ++n) {
            int o = wv * 64 + n * 16 + mrow;
            float S  = __hip_atomic_load(&stats[o],       __ATOMIC_RELAXED, __HIP_MEMORY_SCOPE_AGENT);
            float S2 = __hip_atomic_load(&stats[512 + o], __ATOMIC_RELAXED, __HIP_MEMORY_SCOPE_AGENT);
            float mean = S * (1.f / 16384.f);
            float var  = S2 * (1.f / 16384.f) - mean * mean;
            float sc = gamma[o] * rsqrtf(var + 1e-5f);
            float be = beta[o];
#pragma unroll
            for (int m = 0; m < 4; ++m) {
                f32x4 v = acc[m][n];
                v.x = fmaxf((v.x - mean) * sc + be, 0.f);
                v.y = fmaxf((v.y - mean) * sc + be, 0.f);
                v.z = fmaxf((v.z - mean) * sc + be, 0.f);
                v.w = fmaxf((v.w - mean) * sc + be, 0.f);
                *(f32x4*)(out + ((size_t)(b * 256 + o)) * HW + h * 64 + m * 16 + quad * 4) = v;
            }
        }
    }
}

extern "C" void kernel_launch(void* const* d_in, const int* in_sizes, int n_in,
                              void* d_out, int out_size, void* d_ws, size_t ws_size,
                              hipStream_t stream) {
    const float* x     = (const float*)d_in[0];
    const float* w_off = (const float*)d_in[1];
    const float* b_off = (const float*)d_in[2];
    const float* w_def = (const float*)d_in[3];
    const float* gamma = (const float*)d_in[4];
    const float* beta  = (const float*)d_in[5];
    float* out = (float*)d_out;

    char* ws = (char*)d_ws;
    uint*   x2    = (uint*)ws;                      // 8,388,608 B
    ushort* bt    = (ushort*)(ws + 8388608);        // 1,179,648 B
    ushort* bt0   = (ushort*)(ws + 9568256);        // 147,456 B
    float*  stats = (float*)(ws + 9715712);         // 4,096 B (sums + sumsq)
    uint*   counter = (uint*)(ws + 9715712 + 4096); // 4 B

    hipMemsetAsync(stats, 0, 4224, stream);
    prep_all<<<10784, 256, 0, stream>>>(x, w_def, w_off, x2, bt, bt0);
    fused_all<<<256, 512, 0, stream>>>(x2, bt, bt0, b_off, gamma, beta, out, stats, counter);
}

// Round 8
// 189.161 us; speedup vs baseline: 1.5799x; 1.5799x over previous
//
#include <hip/hip_runtime.h>
#include <hip/hip_bf16.h>

typedef unsigned int  uint;
typedef unsigned short ushort;
typedef short bf16x8 __attribute__((ext_vector_type(8)));
typedef float f32x4  __attribute__((ext_vector_type(4)));

#define HW 4096
#define KD 2304

__device__ __forceinline__ void load_lds16(const void* g, void* l) {
    __builtin_amdgcn_global_load_lds((const __attribute__((address_space(1))) void*)g,
                                     (__attribute__((address_space(3))) void*)l, 16, 0, 0);
}
__device__ __forceinline__ float blo(uint u) { return __uint_as_float(u << 16); }
__device__ __forceinline__ float bhi(uint u) { return __uint_as_float(u & 0xffff0000u); }
__device__ __forceinline__ uint pack2(float e, float o) {
    __hip_bfloat16 he = __float2bfloat16(e), ho = __float2bfloat16(o);
    return (uint)(*(ushort*)&he) | ((uint)(*(ushort*)&ho) << 16);
}

// ---- preps (R5-proven, separate kernels) ----
__global__ void prep_x2(const float* __restrict__ x, uint* __restrict__ x2) {
    int idx = blockIdx.x * 256 + threadIdx.x;
    int a  = idx & 4095;
    int cp = (idx >> 12) & 127;
    int b  = idx >> 19;
    const float* p = x + ((size_t)(b * 256 + 2 * cp)) * HW + a;
    x2[idx] = pack2(p[0], p[HW]);
}
__global__ void prep_bt(const float* __restrict__ w_def, ushort* __restrict__ bt) {
    int idx = blockIdx.x * 256 + threadIdx.x;
    int c   = idx & 255;
    int tap = (idx >> 8) % 9;
    int o   = idx / KD;
    __hip_bfloat16 h = __float2bfloat16(w_def[(o * 256 + c) * 9 + tap]);
    bt[idx] = *(ushort*)&h;
}
__global__ void prep_bt0(const float* __restrict__ w_off, ushort* __restrict__ bt0) {
    int idx = blockIdx.x * 256 + threadIdx.x;
    int c   = idx & 255;
    int tap = (idx >> 8) % 9;
    int j   = idx / KD;
    float v = (j < 18) ? w_off[(j * 256 + c) * 9 + tap] : 0.f;
    __hip_bfloat16 h = __float2bfloat16(v);
    bt0[idx] = *(ushort*)&h;
}

// ---- offset conv (R4-proven) ----
__global__ __launch_bounds__(256) void gemm_off(const uint* __restrict__ x2,
                                                const ushort* __restrict__ bt0,
                                                const float* __restrict__ b_off,
                                                float* __restrict__ off) {
    int id = blockIdx.x;
    int xcd = id & 7;
    int b = xcd >> 1, h = (xcd & 1) * 32 + (id >> 3);
    int t = threadIdx.x, wv = t >> 6, lane = t & 63;
    int mrow = lane & 15, quad = lane >> 4;

    __shared__ uint   lX[3 * 32 * 64];
    __shared__ ushort lB[32 * 576];

    f32x4 acc[2];
    acc[0] = {0.f, 0.f, 0.f, 0.f};
    acc[1] = {0.f, 0.f, 0.f, 0.f};

    for (int cb = 0; cb < 4; ++cb) {
#pragma unroll
        for (int s = 0; s < 6; ++s) {
            int q  = s * 4 + wv;
            int dy = q >> 3;
            int y  = h + dy - 1;
            int dl = (q & 7) * 256 + lane * 4;
            int cp = dl >> 6, w4 = dl & 63;
            if ((unsigned)y < 64u) {
                const uint* src = x2 + ((size_t)(b * 128 + cb * 32 + cp)) * HW + y * 64 + w4;
                load_lds16(src, &lX[q * 256]);
            } else {
                uint4 z = {0u, 0u, 0u, 0u};
                *(uint4*)&lX[q * 256 + lane * 4] = z;
            }
        }
#pragma unroll
        for (int s = 0; s < 9; ++s) {
            int q = s * 4 + wv;
            int e = q * 512 + lane * 8;
            int o  = e / 576;
            int r  = e - o * 576;
            int chp = r >> 3;
            int ch  = chp ^ (o & 7);
            int tap = ch >> 3, k8 = ch & 7;
            const ushort* src = bt0 + (size_t)o * KD + tap * 256 + cb * 64 + k8 * 8;
            load_lds16(src, &lB[q * 512]);
        }
        __syncthreads();
#pragma unroll
        for (int tap = 0; tap < 9; ++tap) {
            int dy = tap / 3, dx = tap % 3;
            int xx = wv * 16 + mrow + dx - 1;
            bool vx = (unsigned)xx < 64u;
#pragma unroll
            for (int kb = 0; kb < 2; ++kb) {
                int cp0 = kb * 16 + quad * 4;
                uint ad[4];
#pragma unroll
                for (int i = 0; i < 4; ++i)
                    ad[i] = vx ? lX[(dy * 32 + cp0 + i) * 64 + xx] : 0u;
                bf16x8 af = *(bf16x8*)ad;
#pragma unroll
                for (int n = 0; n < 2; ++n) {
                    int o = n * 16 + mrow;
                    int chs = tap * 8 + ((kb * 4 + quad) ^ (o & 7));
                    bf16x8 bfr = *(const bf16x8*)&lB[o * 576 + chs * 8];
                    acc[n] = __builtin_amdgcn_mfma_f32_16x16x32_bf16(af, bfr, acc[n], 0, 0, 0);
                }
            }
        }
        __syncthreads();
    }
#pragma unroll
    for (int n = 0; n < 2; ++n) {
        int o = n * 16 + mrow;
        float bias = (o < 18) ? b_off[o] : 0.f;
        f32x4 v = acc[n];
        v.x += bias; v.y += bias; v.z += bias; v.w += bias;
        int wpos = wv * 16 + quad * 4;
        *(f32x4*)(off + ((size_t)(b * 32 + o)) * HW + h * 64 + wpos) = v;
    }
}

// ---- fused gather + main GEMM + stats (R4 cooperative structure, 80 KB LDS) ----
__global__ __launch_bounds__(512) void fused_main(const uint* __restrict__ x2,
                                                  const ushort* __restrict__ bt,
                                                  const float* __restrict__ off,
                                                  float* __restrict__ out,
                                                  float* __restrict__ stats) {
    int id = blockIdx.x;                      // 256 blocks
    int xcd = id & 7;
    int b = xcd >> 1, h = (xcd & 1) * 32 + (id >> 3);
    int t = threadIdx.x;
    int wv = t >> 6, lane = t & 63;
    int mrow = lane & 15, quad = lane >> 4;
    int pw = t & 63;                          // pos (gather role)
    int cg = t >> 6;                          // channel-chunk 0..7 (gather role)

    __shared__ ushort lA[2][64 * 64];         // 2 x 8 KB
    __shared__ ushort lB[2][256 * 64];        // 2 x 32 KB   -> 80 KB total

    // 18 per-pos offsets in registers (coords recomputed per tap; R5-verified math)
    float oy0,oy1,oy2,oy3,oy4,oy5,oy6,oy7,oy8;
    float ox0,ox1,ox2,ox3,ox4,ox5,ox6,ox7,ox8;
    {
        const float* op = off + (size_t)(b * 32) * HW + h * 64 + pw;
        oy0 = op[ 0*HW]; ox0 = op[ 1*HW];
        oy1 = op[ 2*HW]; ox1 = op[ 3*HW];
        oy2 = op[ 4*HW]; ox2 = op[ 5*HW];
        oy3 = op[ 6*HW]; ox3 = op[ 7*HW];
        oy4 = op[ 8*HW]; ox4 = op[ 9*HW];
        oy5 = op[10*HW]; ox5 = op[11*HW];
        oy6 = op[12*HW]; ox6 = op[13*HW];
        oy7 = op[14*HW]; ox7 = op[15*HW];
        oy8 = op[16*HW]; ox8 = op[17*HW];
    }

    int a0=0,a1=0,a2=0,a3=0;
    float f0=0,f1=0,f2=0,f3=0;
    auto coords = [&](int tap) {
        float oy, ox;
        switch (tap) {
            case 0: oy=oy0; ox=ox0; break;  case 1: oy=oy1; ox=ox1; break;
            case 2: oy=oy2; ox=ox2; break;  case 3: oy=oy3; ox=ox3; break;
            case 4: oy=oy4; ox=ox4; break;  case 5: oy=oy5; ox=ox5; break;
            case 6: oy=oy6; ox=ox6; break;  case 7: oy=oy7; ox=ox7; break;
            default: oy=oy8; ox=ox8; break;
        }
        float py = oy + (float)(tap / 3 + h - 1);
        float px = ox + (float)(tap % 3 + pw - 1);
        float y0f = floorf(py), x0f = floorf(px);
        float wy1 = py - y0f, wx1 = px - x0f;
        float wy0 = 1.f - wy1, wx0 = 1.f - wx1;
        bool vy0 = (y0f >= 0.f) && (y0f <= 63.f);
        bool vy1 = (y0f >= -1.f) && (y0f <= 62.f);
        bool vx0 = (x0f >= 0.f) && (x0f <= 63.f);
        bool vx1 = (x0f >= -1.f) && (x0f <= 62.f);
        int iy0 = min(max((int)y0f, 0), 63),  iy1 = min(max((int)y0f + 1, 0), 63);
        int ix0 = min(max((int)x0f, 0), 63),  ix1 = min(max((int)x0f + 1, 0), 63);
        a0 = iy0 * 64 + ix0; a1 = iy0 * 64 + ix1;
        a2 = iy1 * 64 + ix0; a3 = iy1 * 64 + ix1;
        f0 = wy0 * wx0 * (float)(vy0 && vx0);
        f1 = wy0 * wx1 * (float)(vy0 && vx1);
        f2 = wy1 * wx0 * (float)(vy1 && vx0);
        f3 = wy1 * wx1 * (float)(vy1 && vx1);
    };

    const uint* xb = x2 + (size_t)(b * 128) * HW;

    f32x4 acc[4][2];
#pragma unroll
    for (int m = 0; m < 4; ++m)
#pragma unroll
        for (int n = 0; n < 2; ++n) acc[m][n] = {0.f, 0.f, 0.f, 0.f};

    // prologue: slice 0 fully staged into buf 0
    {
        coords(0);
        const uint* xp = xb + (size_t)(cg * 4) * HW;   // tap 0, cb 0
        uint r[4];
#pragma unroll
        for (int j = 0; j < 4; ++j) {
            const uint* p = xp + (size_t)j * HW;
            uint u0 = p[a0], u1 = p[a1], u2 = p[a2], u3 = p[a3];
            float e = f0 * blo(u0) + f1 * blo(u1) + f2 * blo(u2) + f3 * blo(u3);
            float o = f0 * bhi(u0) + f1 * bhi(u1) + f2 * bhi(u2) + f3 * bhi(u3);
            r[j] = pack2(e, o);
        }
        *(uint4*)&lA[0][pw * 64 + ((cg ^ (pw & 7)) * 8)] = *(uint4*)r;
#pragma unroll
        for (int s2 = 0; s2 < 4; ++s2) {
            int e2 = s2 * 512 + t;
            int o2 = e2 >> 3;
            int k8 = (e2 & 7) ^ (o2 & 7);
            const ushort* src = bt + (size_t)o2 * KD + /*tap*/0 * 256 + /*cb*/0 * 64 + k8 * 8;
            load_lds16(src, &lB[0][(e2 & ~63) * 8]);
        }
    }

    int buf = 0;
    for (int s = 0; s < 36; ++s) {
        __syncthreads();                      // slice s visible in buf
        bool more = (s + 1) < 36;
        uint4 g;
        if (more) {
            int sn = s + 1;
            int tap = sn >> 2, cb = sn & 3;
            if ((sn & 3) == 0) coords(tap);
            const uint* xp = xb + (size_t)(cb * 32 + cg * 4) * HW;
            uint r[4];
#pragma unroll
            for (int j = 0; j < 4; ++j) {
                const uint* p = xp + (size_t)j * HW;
                uint u0 = p[a0], u1 = p[a1], u2 = p[a2], u3 = p[a3];
                float e = f0 * blo(u0) + f1 * blo(u1) + f2 * blo(u2) + f3 * blo(u3);
                float o = f0 * bhi(u0) + f1 * bhi(u1) + f2 * bhi(u2) + f3 * bhi(u3);
                r[j] = pack2(e, o);
            }
            g = *(uint4*)r;
#pragma unroll
            for (int s2 = 0; s2 < 4; ++s2) {
                int e2 = s2 * 512 + t;
                int o2 = e2 >> 3;
                int k8 = (e2 & 7) ^ (o2 & 7);
                const ushort* src = bt + (size_t)o2 * KD + tap * 256 + cb * 64 + k8 * 8;
                load_lds16(src, &lB[buf ^ 1][(e2 & ~63) * 8]);
            }
        }
        // MFMA on buf (overlaps the in-flight gather loads above)
#pragma unroll
        for (int kb = 0; kb < 2; ++kb) {
            bf16x8 af[4];
#pragma unroll
            for (int m = 0; m < 4; ++m) {
                int r = m * 16 + mrow;
                af[m] = *(const bf16x8*)&lA[buf][r * 64 + (((kb * 4 + quad) ^ (r & 7)) * 8)];
            }
#pragma unroll
            for (int n = 0; n < 2; ++n) {
                int r = wv * 32 + n * 16 + mrow;
                bf16x8 bfr = *(const bf16x8*)&lB[buf][r * 64 + (((kb * 4 + quad) ^ (r & 7)) * 8)];
#pragma unroll
                for (int m = 0; m < 4; ++m)
                    acc[m][n] = __builtin_amdgcn_mfma_f32_16x16x32_bf16(af[m], bfr, acc[m][n], 0, 0, 0);
            }
        }
        if (more)
            *(uint4*)&lA[buf ^ 1][pw * 64 + ((cg ^ (pw & 7)) * 8)] = g;
        buf ^= 1;
    }

    // ---- epilogue: store raw out + stats atomics (R4-proven) ----
#pragma unroll
    for (int n = 0; n < 2; ++n) {
        int o = wv * 32 + n * 16 + mrow;
        float ss = 0.f, qq = 0.f;
#pragma unroll
        for (int m = 0; m < 4; ++m) {
            f32x4 v = acc[m][n];
            *(f32x4*)(out + ((size_t)(b * 256 + o)) * HW + h * 64 + m * 16 + quad * 4) = v;
            ss += v.x + v.y + v.z + v.w;
            qq += v.x * v.x + v.y * v.y + v.z * v.z + v.w * v.w;
        }
        ss += __shfl_xor(ss, 16); ss += __shfl_xor(ss, 32);
        qq += __shfl_xor(qq, 16); qq += __shfl_xor(qq, 32);
        if (quad == 0) {
            atomicAdd(&stats[o], ss);
            atomicAdd(&stats[512 + o], qq);
        }
    }
}

// ---- BN finalize + apply (R4-proven) ----
__global__ void bn_finalize(const float* __restrict__ stats,
                            const float* __restrict__ gamma,
                            float* __restrict__ ms) {
    int o = threadIdx.x;
    float S = stats[o], S2 = stats[512 + o];
    float m  = S / 16384.f;
    float var = S2 / 16384.f - m * m;
    ms[o]       = m;
    ms[256 + o] = gamma[o] * rsqrtf(var + 1e-5f);
}

__global__ void bn_apply(float* __restrict__ out,
                         const float* __restrict__ ms,
                         const float* __restrict__ beta) {
    int idx4 = blockIdx.x * 256 + threadIdx.x;
    int o = (idx4 >> 10) & 255;
    float4 v = ((const float4*)out)[idx4];
    float mu = ms[o], sc = ms[256 + o], be = beta[o];
    v.x = fmaxf((v.x - mu) * sc + be, 0.f);
    v.y = fmaxf((v.y - mu) * sc + be, 0.f);
    v.z = fmaxf((v.z - mu) * sc + be, 0.f);
    v.w = fmaxf((v.w - mu) * sc + be, 0.f);
    ((float4*)out)[idx4] = v;
}

extern "C" void kernel_launch(void* const* d_in, const int* in_sizes, int n_in,
                              void* d_out, int out_size, void* d_ws, size_t ws_size,
                              hipStream_t stream) {
    const float* x     = (const float*)d_in[0];
    const float* w_off = (const float*)d_in[1];
    const float* b_off = (const float*)d_in[2];
    const float* w_def = (const float*)d_in[3];
    const float* gamma = (const float*)d_in[4];
    const float* beta  = (const float*)d_in[5];
    float* out = (float*)d_out;

    char* ws = (char*)d_ws;
    uint*   x2    = (uint*)ws;                      // 8,388,608 B
    ushort* bt    = (ushort*)(ws + 8388608);        // 1,179,648 B
    ushort* bt0   = (ushort*)(ws + 9568256);        // 147,456 B
    float*  off   = (float*)(ws + 9715712);         // 2,097,152 B
    float*  stats = (float*)(ws + 11812864);        // 4,096 B
    float*  ms    = (float*)(ws + 11816960);        // 2,048 B

    hipMemsetAsync(stats, 0, 4096, stream);
    prep_x2 <<<8192, 256, 0, stream>>>(x, x2);
    prep_bt <<<2304, 256, 0, stream>>>(w_def, bt);
    prep_bt0<<<288,  256, 0, stream>>>(w_off, bt0);
    gemm_off<<<256, 256, 0, stream>>>(x2, bt0, b_off, off);
    fused_main<<<256, 512, 0, stream>>>(x2, bt, off, out, stats);
    bn_finalize<<<1, 256, 0, stream>>>(stats, gamma, ms);
    bn_apply<<<4096, 256, 0, stream>>>(out, ms, beta);
}